// Round 1
// baseline (126.928 us; speedup 1.0000x reference)
//
#include <hip/hip_runtime.h>
#include <cmath>

// Static problem config (matches reference)
#define RB 20
#define RA 19
#define NPT (RB*RA)
#define DZ 25
#define DIN 9
#define MULT 128
#define CH 128

// ---------------------------------------------------------------------------
// Device-side Gaunt table builder. Replaces the captured pageable H2D memcpy
// (which cost ~55us/replay as a graph node) with a ~5us kernel. Same
// algorithm as the previous host builder (GL Newton + Legendre recurrence +
// exact quadrature) in fp64 -> table identical to ~1e-14, absmax preserved.
// One block per (d1,d2) pair; phases: GL nodes -> Y table in LDS -> reduce.
__global__ __launch_bounds__(256) void gaunt_build(float* __restrict__ out) {
    __shared__ double xq[RB], wq[RB], nlmv[DZ];
    __shared__ double Yd[DZ][NPT];
    __shared__ double qwp[NPT];
    const int tid = threadIdx.x;
    const double PI = 3.14159265358979323846;

    // Phase 1a: Gauss-Legendre nodes/weights (threads 0..19)
    if (tid < RB) {
        double x = cos(PI * (tid + 0.75) / (RB + 0.5));
        double dp = 0.0;
        for (int it = 0; it < 100; ++it) {
            double p0 = 1.0, p1 = x;
            for (int k = 2; k <= RB; ++k) {
                double p2 = ((2.0*k - 1.0)*x*p1 - (k - 1.0)*p0) / (double)k;
                p0 = p1; p1 = p2;
            }
            dp = RB * (x*p1 - p0) / (x*x - 1.0);
            double dx = p1 / dp;
            x -= dx;
            if (fabs(dx) < 1e-15) break;
        }
        {
            double p0 = 1.0, p1 = x;
            for (int k = 2; k <= RB; ++k) {
                double p2 = ((2.0*k - 1.0)*x*p1 - (k - 1.0)*p0) / (double)k;
                p0 = p1; p1 = p2;
            }
            dp = RB * (x*p1 - p0) / (x*x - 1.0);
        }
        xq[tid] = x;
        wq[tid] = 2.0 / ((1.0 - x*x)*dp*dp);
    }
    // Phase 1b: normalization constants (threads 64..88), incl sqrt(2) for m!=0
    if (tid >= 64 && tid < 64 + DZ) {
        int idx = tid - 64;
        int l = 0;
        while ((l + 1)*(l + 1) <= idx) ++l;
        int m = idx - l*l - l;
        int am = m < 0 ? -m : m;
        double fr = 1.0;
        for (int i = l - am + 1; i <= l + am; ++i) fr *= (double)i;
        nlmv[idx] = sqrt((2.0*l + 1.0) / (4.0*PI) / fr) * ((m == 0) ? 1.0 : sqrt(2.0));
    }
    __syncthreads();

    // Phase 2: Y[lm][point] table in LDS (fp64)
    for (int p = tid; p < NPT; p += 256) {
        const int b = p / RA, a = p - b*RA;
        double ct = xq[b], st = sqrt(fmax(0.0, 1.0 - ct*ct));
        double P[5][5];
        double pmm = 1.0;
        for (int m = 0; m <= 4; ++m) {
            if (m > 0) pmm *= -(2.0*m - 1.0) * st;
            P[m][m] = pmm;
            if (m < 4) {
                double pp = pmm, pc = ct*(2.0*m + 1.0)*pmm;
                P[m+1][m] = pc;
                for (int l = m + 2; l <= 4; ++l) {
                    double pn = ((2.0*l - 1.0)*ct*pc - (double)(l + m - 1)*pp) / (double)(l - m);
                    P[l][m] = pn; pp = pc; pc = pn;
                }
            }
        }
        double alpha = 2.0*PI*(double)a/(double)RA;
        double ca = cos(alpha), sa = sin(alpha);
        double cm = 1.0, sm = 0.0;   // cos(m*alpha), sin(m*alpha) via recurrence
        qwp[p] = wq[b] * (2.0*PI/(double)RA);
        for (int am = 0; am <= 4; ++am) {
            if (am > 0) {
                double c2 = cm*ca - sm*sa, s2 = sm*ca + cm*sa;
                cm = c2; sm = s2;
            }
            for (int l = am; l <= 4; ++l) {
                if (am == 0) {
                    Yd[l*l + l][p] = nlmv[l*l + l] * P[l][0];
                } else {
                    Yd[l*l + l + am][p] = nlmv[l*l + l + am] * P[l][am] * cm;
                    Yd[l*l + l - am][p] = nlmv[l*l + l - am] * P[l][am] * sm;
                }
            }
        }
    }
    __syncthreads();

    // Phase 3: G[dz][d1,d2] = sum_p Y[dz]Y[d1]Y[d2] qw ; wave-per-dz-stripe
    const int pr = blockIdx.x;            // 0..80 = d1*9+d2
    const int d1 = pr / 9, d2 = pr - 9*d1;
    const int lane = tid & 63;
    const int wave = tid >> 6;
    for (int dz = wave; dz < DZ; dz += 4) {
        double s = 0.0;
        for (int p = lane; p < NPT; p += 64)
            s += Yd[dz][p] * Yd[d1][p] * Yd[d2][p] * qwp[p];
        for (int off = 32; off >= 1; off >>= 1)
            s += __shfl_down(s, off, 64);
        if (lane == 0) out[pr*28 + dz] = (float)s;
    }
    if (tid == 0) { out[pr*28 + 25] = 0.f; out[pr*28 + 26] = 0.f; out[pr*28 + 27] = 0.f; }
}

// ---------------------------------------------------------------------------
// Stage D helper: wave-pair owns l-aligned d-range [D0,D0+ND), each wave one
// e-half (e column set). wz[l] columns read once per block total. z read as
// float4 broadcasts; l is compile-time -> w loads CSE'd across same-l i.
template<int D0, int ND>
__device__ __forceinline__ void d_tile(const float* sZ, const float* __restrict__ wz,
                                       float* sOut, int e) {
    const float s128 = 0.08838834764831845f;
    float acc[ND * 2];                    // [i][node]
    #pragma unroll
    for (int i = 0; i < ND * 2; ++i) acc[i] = 0.f;
    for (int c0 = 0; c0 < CH; c0 += 4) {
        #pragma unroll
        for (int i = 0; i < ND; ++i) {
            const int d = D0 + i;
            const int l = (d == 0) ? 0 : (d < 4) ? 1 : (d < 9) ? 2 : (d < 16) ? 3 : 4;
            float4 z0 = *(const float4*)(sZ + d * 128 + c0);          // node0 broadcast
            float4 z1 = *(const float4*)(sZ + (25 + d) * 128 + c0);   // node1 broadcast
            #pragma unroll
            for (int k = 0; k < 4; ++k) {
                float wv = wz[l * 16384 + (c0 + k) * 128 + e];        // CSE across same-l i
                float zc0 = (k == 0) ? z0.x : (k == 1) ? z0.y : (k == 2) ? z0.z : z0.w;
                float zc1 = (k == 0) ? z1.x : (k == 1) ? z1.y : (k == 2) ? z1.z : z1.w;
                acc[i*2+0] = fmaf(zc0, wv, acc[i*2+0]);
                acc[i*2+1] = fmaf(zc1, wv, acc[i*2+1]);
            }
        }
    }
    #pragma unroll
    for (int i = 0; i < ND; ++i) {
        sOut[e * 25 + D0 + i]         = acc[i*2+0] * s128;
        sOut[(128 + e) * 25 + D0 + i] = acc[i*2+1] * s128;
    }
}

// ---------------------------------------------------------------------------
// Fully fused, 2 nodes per block, z in LDS. 512 threads / 8 waves so that
// 2 resident blocks give 16 waves/CU (was 8) -- occupancy was the bottleneck
// (VALUBusy 46%, Occupancy 19%). Per-output arithmetic order identical to the
// 256-thread version -> bitwise-same results. Weight L2 traffic unchanged:
// stage B packs the node pair into lane halves; stage D splits e-halves.
__global__ __launch_bounds__(512, 4) void gaunt_fused(
    const float* __restrict__ xg, const float* __restrict__ yg,
    const float* __restrict__ wxg, const float* __restrict__ wyg,
    const float* __restrict__ wzg, float* __restrict__ outg,
    const float* __restrict__ gGt) {

    // LDS pool (floats), 15616 = 62464 B:
    //  sZ   [0,     6400)  z [n][dz][c]
    //  sXY  [6400, 11008)  x,y transposed [side][n][d*128+m]  (stages A/B)
    //  sG   [6400,  8668)  Gaunt table (stage C; aliases dead sXY)
    //  sOut [6400, 12800)  out [n][e][25]  (stage D/E)
    //  sXc  [11008,15616)  xc [side][d][n][c]  (stages B/C)
    __shared__ __align__(16) float pool[15616];
    float* sZ   = pool;
    float* sXY  = pool + 6400;
    float* sG   = pool + 6400;
    float* sOut = pool + 6400;
    float* sXc  = pool + 11008;

    const int tid  = threadIdx.x;
    const int b    = blockIdx.x;
    const int lane = tid & 63;
    const int wave = __builtin_amdgcn_readfirstlane(tid >> 6);
    const float s128 = 0.08838834764831845f;   // 1/sqrt(128)

    // Stage A: load x,y for nodes 2b,2b+1; transpose to [side][n][d*128+m]
    {
        const float4* xs = (const float4*)(xg + 2 * b * 1152);
        const float4* ys = (const float4*)(yg + 2 * b * 1152);
        for (int i = tid; i < 1152; i += 512) {
            float4 v = (i < 576) ? xs[i] : ys[i - 576];
            int r = (i < 576) ? i : i - 576;
            int base = (i < 576) ? 0 : 2304;
            int j0 = r * 4;
            #pragma unroll
            for (int k = 0; k < 4; ++k) {
                int j = j0 + k;
                int n = j / 1152;
                int jj = j - n * 1152;
                int m = jj / 9, d = jj - 9 * m;
                float val = (k == 0) ? v.x : (k == 1) ? v.y : (k == 2) ? v.z : v.w;
                sXY[base + n * 1152 + d * 128 + m] = val;
            }
        }
    }
    __syncthreads();

    // Stage B: linear_in. wave=(side,cquarter); lane=(node, c-sub).
    // Each w element still fetched once per block (128B/instr, node pair
    // shares the fetch), so w L2 traffic is unchanged vs 256-thread version.
    {
        const int side = wave >> 2, cq = wave & 3;
        const int nn = lane >> 5;                 // node within pair
        const int c  = cq * 32 + (lane & 31);
        const float* wb = side ? wyg : wxg;
        const float* xb = sXY + side * 2304 + nn * 1152;   // [d*128+m]
        float acc[9];                              // [d]
        #pragma unroll
        for (int i = 0; i < 9; ++i) acc[i] = 0.f;
        for (int m0 = 0; m0 < MULT; m0 += 4) {
            float w0[4], w1[4], w2[4];
            #pragma unroll
            for (int k = 0; k < 4; ++k) {
                w0[k] = wb[(m0 + k) * 128 + c];
                w1[k] = wb[16384 + (m0 + k) * 128 + c];
                w2[k] = wb[32768 + (m0 + k) * 128 + c];
            }
            #pragma unroll
            for (int d = 0; d < 9; ++d) {
                const float* wl = (d == 0) ? w0 : (d < 4) ? w1 : w2;
                float4 x0 = *(const float4*)(xb + d * 128 + m0);   // 2-way broadcast
                acc[d] = fmaf(x0.x, wl[0], acc[d]);
                acc[d] = fmaf(x0.y, wl[1], acc[d]);
                acc[d] = fmaf(x0.z, wl[2], acc[d]);
                acc[d] = fmaf(x0.w, wl[3], acc[d]);
            }
        }
        #pragma unroll
        for (int d = 0; d < 9; ++d)
            sXc[((side * 9 + d) * 2 + nn) * 128 + c] = acc[d] * s128;
    }
    __syncthreads();

    // Stage B2: Gaunt table -> LDS (over dead sXY), float4 copy
    for (int i = tid; i < 567; i += 512)
        ((float4*)sG)[i] = ((const float4*)gGt)[i];
    __syncthreads();

    // Stage C: z[n][dz][c] = sum_{d1,d2} G[dz][d1,d2] xc[d1][c] yc[d2][c]
    // 512 threads = (node, dz-half, c); halves split 12/13 so both G-row
    // offsets (0 and 12 floats = 48 B) are 16B-aligned: 3x ds_read_b128 + 1x
    // b32 per (d1,d2).
    {
        const int c    = tid & 127;
        const int half = (tid >> 7) & 1;          // wave-uniform
        const int nn   = tid >> 8;                // wave-uniform
        const int dz0  = half ? 12 : 0;
        float xr[9], yr[9];
        #pragma unroll
        for (int d = 0; d < 9; ++d) {
            xr[d] = sXc[(d * 2 + nn) * 128 + c];
            yr[d] = sXc[((9 + d) * 2 + nn) * 128 + c];
        }
        float a0[13];
        #pragma unroll
        for (int i = 0; i < 13; ++i) a0[i] = 0.f;
        for (int d1 = 0; d1 < 9; ++d1) {
            #pragma unroll
            for (int d2 = 0; d2 < 9; ++d2) {
                float p0 = xr[d1] * yr[d2];
                const float* gt = sG + (d1 * 9 + d2) * 28 + dz0;   // 16B-aligned
                float4 g0 = *(const float4*)gt;
                float4 g1 = *(const float4*)(gt + 4);
                float4 g2 = *(const float4*)(gt + 8);
                float  g3 = gt[12];            // half0: unused d12 dup; half1: dz24
                float gv[13] = {g0.x,g0.y,g0.z,g0.w, g1.x,g1.y,g1.z,g1.w,
                                g2.x,g2.y,g2.z,g2.w, g3};
                #pragma unroll
                for (int i = 0; i < 13; ++i)
                    a0[i] = fmaf(p0, gv[i], a0[i]);
            }
        }
        if (half == 0) {
            #pragma unroll
            for (int i = 0; i < 12; ++i)        // dz 0..11 (a0[12] discarded)
                sZ[(nn * 25 + i) * 128 + c] = a0[i];
        } else {
            #pragma unroll
            for (int i = 0; i < 13; ++i)        // dz 12..24
                sZ[(nn * 25 + 12 + i) * 128 + c] = a0[i];
        }
    }
    __syncthreads();   // sZ ready; sG/sXc dead -> sOut may alias

    // Stage D: linear_out. 8 waves = (l-aligned d-group, e-half); each wz
    // column still read once per block.
    {
        const int dg = wave >> 1;
        const int e  = (wave & 1) * 64 + lane;
        if      (dg == 0) d_tile<0, 4>(sZ, wzg, sOut, e);   // l0+l1
        else if (dg == 1) d_tile<4, 5>(sZ, wzg, sOut, e);   // l2
        else if (dg == 2) d_tile<9, 7>(sZ, wzg, sOut, e);   // l3
        else              d_tile<16, 9>(sZ, wzg, sOut, e);  // l4
    }
    __syncthreads();

    // Stage E: coalesced float4 store of both nodes' outputs
    float* po = outg + 2 * b * (CH * DZ);
    const float4* so = (const float4*)sOut;
    for (int j = tid; j < (2 * CH * DZ) / 4; j += 512)
        ((float4*)po)[j] = so[j];
}

extern "C" void kernel_launch(void* const* d_in, const int* in_sizes, int n_in,
                              void* d_out, int out_size, void* d_ws, size_t ws_size,
                              hipStream_t stream) {
    int N = in_sizes[0] / (MULT * DIN);

    // Build the Gaunt table on-device (replaces pageable H2D memcpy node)
    hipLaunchKernelGGL(gaunt_build, dim3(81), dim3(256), 0, stream, (float*)d_ws);

    hipLaunchKernelGGL(gaunt_fused, dim3(N / 2), dim3(512), 0, stream,
                       (const float*)d_in[0], (const float*)d_in[1],
                       (const float*)d_in[2], (const float*)d_in[3],
                       (const float*)d_in[4], (float*)d_out, (const float*)d_ws);
}